// Round 1
// baseline (134.918 us; speedup 1.0000x reference)
//
#include <hip/hip_runtime.h>

#define NQB   12
#define NST   4096      // 2^12 amplitudes
#define NLAY  6
#define NCLS  64
#define NPASS 84        // 12 embedding RX + 6*12 layer RX
#define TPB   512

struct QMasks {
    int m[NPASS];     // XOR pair-mask for each RX pass
    int meas[NQB];    // parity masks for <Z_w> signs (rows of (f^6)^-1)
};

__global__ __launch_bounds__(TPB) void qnn_kernel(
    const float* __restrict__ x, const float* __restrict__ qw,
    const float* __restrict__ W, const float* __restrict__ bias,
    float* __restrict__ out, QMasks mk)
{
    __shared__ float2 st[NST];                 // statevector (re, im)
    __shared__ float2 cs[NPASS];               // (cos(th/2), sin(th/2)) per pass
    __shared__ float  zpart[TPB / 64][NQB];
    __shared__ float  zfin[NQB];

    const int tid = threadIdx.x;
    const int b   = blockIdx.x;

    // init |0...0> and the per-pass angle table
    for (int i = tid; i < NST; i += TPB)
        st[i] = make_float2(i == 0 ? 1.f : 0.f, 0.f);
    if (tid < NPASS) {
        float th = (tid < NQB) ? x[b * NQB + tid] : qw[tid - NQB];
        float h = 0.5f * th;
        cs[tid] = make_float2(cosf(h), sinf(h));
    }
    __syncthreads();

    // 84 RX passes; CNOT rings are folded into the masks (deferred permutation)
    #pragma unroll 1
    for (int g = 0; g < NPASS; ++g) {
        const int   m    = mk.m[g];
        const float c    = cs[g].x;
        const float sv   = cs[g].y;
        const int   hb   = __ffs(m) - 1;       // any set bit of m (uniform)
        const int   lowm = (1 << hb) - 1;
        #pragma unroll
        for (int it = 0; it < (NST / 2) / TPB; ++it) {
            int p  = tid + it * TPB;
            int s0 = ((p & ~lowm) << 1) | (p & lowm);  // insert 0 at bit hb
            int s1 = s0 ^ m;
            float2 a  = st[s0];
            float2 bb = st[s1];
            // RX is symmetric: n_x = c*a_x - i*sv*a_xbar
            float2 n0 = make_float2(fmaf(c, a.x,  sv * bb.y),
                                    fmaf(c, a.y, -sv * bb.x));
            float2 n1 = make_float2(fmaf(c, bb.x,  sv * a.y),
                                    fmaf(c, bb.y, -sv * a.x));
            st[s0] = n0;
            st[s1] = n1;
        }
        __syncthreads();
    }

    // <Z_w> via signed probability sums; signs are parities in stored space
    float zacc[NQB];
    #pragma unroll
    for (int w = 0; w < NQB; ++w) zacc[w] = 0.f;
    for (int i = tid; i < NST; i += TPB) {
        float2 a = st[i];
        float pr = fmaf(a.x, a.x, a.y * a.y);
        #pragma unroll
        for (int w = 0; w < NQB; ++w)
            zacc[w] += (__popc(i & mk.meas[w]) & 1) ? -pr : pr;
    }

    const int lane = tid & 63, wid = tid >> 6;
    #pragma unroll
    for (int w = 0; w < NQB; ++w) {
        float v = zacc[w];
        #pragma unroll
        for (int off = 32; off > 0; off >>= 1) v += __shfl_down(v, off);
        if (lane == 0) zpart[wid][w] = v;
    }
    __syncthreads();
    if (tid < NQB) {
        float v = 0.f;
        #pragma unroll
        for (int k = 0; k < TPB / 64; ++k) v += zpart[k][tid];
        zfin[tid] = v;
    }
    __syncthreads();
    // classifier head: out[b, c] = bias[c] + sum_w z[w] * W[c, w]
    if (tid < NCLS) {
        float acc = bias[tid];
        #pragma unroll
        for (int w = 0; w < NQB; ++w) acc += zfin[w] * W[tid * NQB + w];
        out[b * NCLS + tid] = acc;
    }
}

// ---- host-side static mask computation (pure CPU, graph-capture safe) ----

static int f_of(int j) {
    // one layer's CNOT ring: gates w=0..11 applied in order; state'[j]=state[f(j)]
    // f = sigma_0 o sigma_1 o ... o sigma_11 evaluated innermost (w=11) first
    for (int w = 11; w >= 0; --w) {
        int pc = 11 - w;
        int pt = 11 - ((w + 1) % 12);
        j ^= ((j >> pc) & 1) << pt;
    }
    return j;
}

static void compute_masks(QMasks* q) {
    // embedding: g = identity -> plain single-bit masks (wire w -> bit 11-w)
    for (int w = 0; w < NQB; ++w) q->m[w] = 1 << (11 - w);
    // layer l RX gates see g = f^l: mask = f^l(2^(11-w))
    for (int l = 0; l < NLAY; ++l)
        for (int w = 0; w < NQB; ++w) {
            int v = 1 << (11 - w);
            for (int t = 0; t < l; ++t) v = f_of(v);
            q->m[NQB + l * NQB + w] = v;
        }
    // measurement: need rows of (f^6)^-1 over GF(2)
    int col[NQB];
    for (int k = 0; k < NQB; ++k) {
        int v = 1 << k;
        for (int t = 0; t < NLAY; ++t) v = f_of(v);
        col[k] = v;
    }
    unsigned rowG[NQB], rowH[NQB];
    for (int r = 0; r < NQB; ++r) {
        unsigned rr = 0;
        for (int k = 0; k < NQB; ++k) rr |= ((unsigned)((col[k] >> r) & 1)) << k;
        rowG[r] = rr;
        rowH[r] = 1u << r;
    }
    for (int k = 0; k < NQB; ++k) {                  // Gauss-Jordan over GF(2)
        int piv = -1;
        for (int r = k; r < NQB; ++r)
            if ((rowG[r] >> k) & 1) { piv = r; break; }
        unsigned tg = rowG[piv], th = rowH[piv];
        rowG[piv] = rowG[k]; rowH[piv] = rowH[k];
        rowG[k] = tg; rowH[k] = th;
        for (int r = 0; r < NQB; ++r)
            if (r != k && ((rowG[r] >> k) & 1)) { rowG[r] ^= rowG[k]; rowH[r] ^= rowH[k]; }
    }
    for (int w = 0; w < NQB; ++w) q->meas[w] = (int)rowH[11 - w];
}

extern "C" void kernel_launch(void* const* d_in, const int* in_sizes, int n_in,
                              void* d_out, int out_size, void* d_ws, size_t ws_size,
                              hipStream_t stream) {
    const float* x    = (const float*)d_in[0];
    const float* qw   = (const float*)d_in[1];
    const float* W    = (const float*)d_in[2];
    const float* bias = (const float*)d_in[3];
    float* out        = (float*)d_out;

    QMasks mk;
    compute_masks(&mk);

    const int batch = in_sizes[0] / NQB;   // 512
    qnn_kernel<<<batch, TPB, 0, stream>>>(x, qw, W, bias, out, mk);
}

// Round 2
// 76.114 us; speedup vs baseline: 1.7726x; 1.7726x over previous
//
#include <hip/hip_runtime.h>

#define NQB   12
#define NST   4096
#define NLAY  6
#define NCLS  64
#define TPB   512
#define NGATE 84      // 12 embedding RX + 6*12 layer RX
#define MAXG  112     // gates + per-bucket even padding

struct KArgs {
    int mlo[MAXG];    // mask low 9 bits (vs tid), bucket-sorted by mask>>9
    int src[MAXG];    // angle source: 0..11 -> x[b,src]; >=12 -> qw[src-12]; -1 pad
    int bstart[9];    // bucket b occupies [bstart[b], bstart[b+1]), even counts
    int tot;
    int meas[NQB];    // parity masks for <Z_w> (rows of (f^6)^-1)
};

__device__ __forceinline__ void fast_sincos(float phi, float* s, float* c) {
    // v_sin/v_cos take revolutions; fract-reduce (phi up to ~150 rad is exact
    // to ~1e-5 rad after the fp32 mul, well under the 6e-4 absmax threshold)
    float rv = phi * 0.15915494309189535f;
    rv -= floorf(rv);
    *s = __builtin_amdgcn_sinf(rv);
    *c = __builtin_amdgcn_cosf(rv);
}

__global__ __launch_bounds__(TPB) void qnn_kernel(
    const float* __restrict__ x, const float* __restrict__ qw,
    const float* __restrict__ W, const float* __restrict__ bias,
    float* __restrict__ out, KArgs A)
{
    __shared__ float2 d[NST];          // d_k = (cos phi_k, sin phi_k)
    __shared__ float  gl[2 * MAXG];    // packed (theta/2, mask_lo9) per gate
    __shared__ float  zpart[TPB / 64][NQB];
    __shared__ float  zfin[NQB];

    const int tid = threadIdx.x;
    const int b   = blockIdx.x;

    // ---- stage packed gate table: (0.5*theta, low-9-bit mask) ----
    if (tid < A.tot) {
        int s = A.src[tid];
        float v = 0.0f;
        if (s >= NQB)      v = 0.5f * qw[s - NQB];
        else if (s >= 0)   v = 0.5f * x[b * NQB + s];
        gl[2 * tid]     = v;
        gl[2 * tid + 1] = __int_as_float(A.mlo[tid]);
    }
    __syncthreads();

    // ---- phase accumulation, bucketed by mask bits 9-11 ----
    // thread owns k = tid + 512*r (r = 0..7). popc(k&m) splits:
    // popc(tid & m_lo9) + popc(r & m_hi3)  ->  8 bucket sums + 3-bit FWHT.
    float B[8];
    #pragma unroll
    for (int i = 0; i < 8; ++i) {
        float acc = 0.f;
        const int e = A.bstart[i + 1];
        for (int j = A.bstart[i]; j < e; j += 2) {       // 2 gates per b128
            float4 g2 = *(const float4*)&gl[2 * j];
            int m0 = __float_as_int(g2.y);
            int m1 = __float_as_int(g2.w);
            acc += (__popc(tid & m0) & 1) ? -g2.x : g2.x;
            acc += (__popc(tid & m1) & 1) ? -g2.z : g2.z;
        }
        B[i] = acc;
    }
    // 3-stage FWHT: B[r] = sum_b (-1)^{popc(r&b)} B0[b] = phi_{tid + 512r}
    #pragma unroll
    for (int s2 = 1; s2 < 8; s2 <<= 1) {
        #pragma unroll
        for (int i = 0; i < 8; ++i)
            if (!(i & s2)) {
                float u = B[i], v = B[i | s2];
                B[i] = u + v; B[i | s2] = u - v;
            }
    }

    float2 myd[8];
    #pragma unroll
    for (int r = 0; r < 8; ++r) {
        float sv, cv;
        fast_sincos(B[r], &sv, &cv);
        myd[r] = make_float2(cv, sv);
        d[tid + (r << 9)] = myd[r];
    }
    __syncthreads();

    // ---- z_w = (1/N) sum_k cos(phi_k - phi_{k^t_w}) via LDS correlation ----
    float acc[NQB];
    #pragma unroll
    for (int w = 0; w < NQB; ++w) acc[w] = 0.f;
    #pragma unroll
    for (int r = 0; r < 8; ++r) {
        const int k = tid + (r << 9);
        const float2 m = myd[r];
        #pragma unroll
        for (int w = 0; w < NQB; ++w) {
            float2 p = d[k ^ A.meas[w]];
            acc[w] = fmaf(m.x, p.x, fmaf(m.y, p.y, acc[w]));
        }
    }

    // ---- reduce 12 sums over 512 threads ----
    const int lane = tid & 63, wid = tid >> 6;
    #pragma unroll
    for (int w = 0; w < NQB; ++w) {
        float v = acc[w];
        #pragma unroll
        for (int off = 32; off > 0; off >>= 1) v += __shfl_down(v, off);
        if (lane == 0) zpart[wid][w] = v;
    }
    __syncthreads();
    if (tid < NQB) {
        float v = 0.f;
        #pragma unroll
        for (int k = 0; k < TPB / 64; ++k) v += zpart[k][tid];
        zfin[tid] = v * (1.0f / NST);
    }
    __syncthreads();

    // ---- classifier head ----
    if (tid < NCLS) {
        float a = bias[tid];
        #pragma unroll
        for (int w = 0; w < NQB; ++w) a += zfin[w] * W[tid * NQB + w];
        out[b * NCLS + tid] = a;
    }
}

// ---- host-side static mask computation (pure CPU, graph-capture safe) ----

static int f_of(int j) {
    for (int w = 11; w >= 0; --w) {
        int pc = 11 - w;
        int pt = 11 - ((w + 1) % 12);
        j ^= ((j >> pc) & 1) << pt;
    }
    return j;
}

static void build_args(KArgs* A) {
    int fm[NGATE], src[NGATE];
    for (int w = 0; w < NQB; ++w) { fm[w] = 1 << (11 - w); src[w] = w; }
    for (int l = 0; l < NLAY; ++l)
        for (int w = 0; w < NQB; ++w) {
            int v = 1 << (11 - w);
            for (int t = 0; t < l; ++t) v = f_of(v);
            fm[NQB + l * NQB + w]  = v;
            src[NQB + l * NQB + w] = NQB + l * NQB + w;   // qw[l*12+w]
        }
    // bucket-sort by mask bits 9-11, pad each bucket to even count
    int tot = 0;
    for (int bkt = 0; bkt < 8; ++bkt) {
        A->bstart[bkt] = tot;
        for (int g = 0; g < NGATE; ++g)
            if ((fm[g] >> 9) == bkt) {
                A->mlo[tot] = fm[g] & 511;
                A->src[tot] = src[g];
                ++tot;
            }
        if (tot & 1) { A->mlo[tot] = 0; A->src[tot] = -1; ++tot; }
    }
    A->bstart[8] = tot;
    A->tot = tot;
    for (int g = tot; g < MAXG; ++g) { A->mlo[g] = 0; A->src[g] = -1; }

    // measurement parities: rows of (f^6)^-1 over GF(2)
    int col[NQB];
    for (int k = 0; k < NQB; ++k) {
        int v = 1 << k;
        for (int t = 0; t < NLAY; ++t) v = f_of(v);
        col[k] = v;
    }
    unsigned rowG[NQB], rowH[NQB];
    for (int r = 0; r < NQB; ++r) {
        unsigned rr = 0;
        for (int k = 0; k < NQB; ++k) rr |= ((unsigned)((col[k] >> r) & 1)) << k;
        rowG[r] = rr;
        rowH[r] = 1u << r;
    }
    for (int k = 0; k < NQB; ++k) {
        int piv = -1;
        for (int r = k; r < NQB; ++r)
            if ((rowG[r] >> k) & 1) { piv = r; break; }
        unsigned tg = rowG[piv], th = rowH[piv];
        rowG[piv] = rowG[k]; rowH[piv] = rowH[k];
        rowG[k] = tg; rowH[k] = th;
        for (int r = 0; r < NQB; ++r)
            if (r != k && ((rowG[r] >> k) & 1)) { rowG[r] ^= rowG[k]; rowH[r] ^= rowH[k]; }
    }
    for (int w = 0; w < NQB; ++w) A->meas[w] = (int)rowH[11 - w];
}

extern "C" void kernel_launch(void* const* d_in, const int* in_sizes, int n_in,
                              void* d_out, int out_size, void* d_ws, size_t ws_size,
                              hipStream_t stream) {
    const float* x    = (const float*)d_in[0];
    const float* qw   = (const float*)d_in[1];
    const float* W    = (const float*)d_in[2];
    const float* bias = (const float*)d_in[3];
    float* out        = (float*)d_out;

    KArgs A;
    build_args(&A);

    const int batch = in_sizes[0] / NQB;   // 512
    qnn_kernel<<<batch, TPB, 0, stream>>>(x, qw, W, bias, out, A);
}

// Round 3
// 72.536 us; speedup vs baseline: 1.8600x; 1.0493x over previous
//
#include <hip/hip_runtime.h>

#define NQB   12
#define NST   4096
#define NLAY  6
#define NCLS  64
#define NGQ   72      // 6 layers x 12 RX gates (sample-independent)
#define TPB   512

struct PhiArgs  { int m[NGQ]; };     // XOR masks for the 72 layer-RX gates
struct MainArgs { int meas[NQB]; };  // parity masks for <Z_w> (rows of (f^6)^-1)

// ---- kernel 1: Phiq[k] = 0.5 * sum_g (-1)^{popc(k & m_g)} * qw[g] ----
__global__ __launch_bounds__(64) void phiq_kernel(
    const float* __restrict__ qw, float* __restrict__ phiq, PhiArgs A)
{
    const int k = blockIdx.x * 64 + threadIdx.x;   // 64 blocks x 64 = 4096
    float acc = 0.f;
    #pragma unroll
    for (int g = 0; g < NGQ; ++g) {
        float v = 0.5f * qw[g];                    // uniform -> scalar load
        acc += (__popc(k & A.m[g]) & 1) ? -v : v;
    }
    phiq[k] = acc;
}

// ---- kernel 2: per-sample phases, Walsh autocorrelation, linear head ----
__global__ __launch_bounds__(TPB) void qnn_kernel(
    const float* __restrict__ x, const float* __restrict__ phiq,
    const float* __restrict__ W, const float* __restrict__ bias,
    float* __restrict__ out, MainArgs A)
{
    __shared__ float2 d[NST];                 // d_k = (cos phi_k, sin phi_k)
    __shared__ float  zpart[TPB / 64][NQB];
    __shared__ float  zfin[NQB];

    const int tid = threadIdx.x;
    const int b   = blockIdx.x;

    // prefetch the sample-independent phases (8 coalesced loads, L1/L2-hot)
    float pq[8];
    #pragma unroll
    for (int r = 0; r < 8; ++r) pq[r] = phiq[tid + (r << 9)];

    // embedding part: masks are single bits (wire w <-> bit 11-w of k).
    // k = tid | (r<<9): bits 0..8 from tid (wires 3..11), bits 9..11 from r
    // (wires 2,1,0).
    float xv[NQB];
    #pragma unroll
    for (int w = 0; w < NQB; ++w) xv[w] = 0.5f * x[b * NQB + w];  // uniform
    float base = 0.f;
    #pragma unroll
    for (int w = 3; w < NQB; ++w)
        base += ((tid >> (11 - w)) & 1) ? -xv[w] : xv[w];
    float c3[8];
    #pragma unroll
    for (int r = 0; r < 8; ++r)
        c3[r] = ((r & 4) ? -xv[0] : xv[0]) + ((r & 2) ? -xv[1] : xv[1])
              + ((r & 1) ? -xv[2] : xv[2]);

    float2 myd[8];
    #pragma unroll
    for (int r = 0; r < 8; ++r) {
        float phi = pq[r] + base + c3[r];
        // v_sin/v_cos take revolutions; fract-reduce (phi ~1e2 rad -> ~1e-5
        // abs phase error after the fp32 mul, far under the 6e-4 threshold)
        float rv = phi * 0.15915494309189535f;
        rv -= floorf(rv);
        float sv = __builtin_amdgcn_sinf(rv);
        float cv = __builtin_amdgcn_cosf(rv);
        myd[r] = make_float2(cv, sv);
        d[tid + (r << 9)] = myd[r];
    }
    __syncthreads();

    // z_w = (1/N) sum_k cos(phi_k - phi_{k^t_w})  (Walsh autocorrelation)
    float acc[NQB];
    #pragma unroll
    for (int w = 0; w < NQB; ++w) acc[w] = 0.f;
    #pragma unroll
    for (int w = 0; w < NQB; ++w) {
        const int u = tid ^ A.meas[w];            // 12-bit xor-partner base
        #pragma unroll
        for (int r = 0; r < 8; ++r) {
            float2 p = d[u ^ (r << 9)];           // addr-xor: 1 VALU op each
            acc[w] = fmaf(myd[r].x, p.x, fmaf(myd[r].y, p.y, acc[w]));
        }
    }

    // reduce 12 sums over 512 threads
    const int lane = tid & 63, wid = tid >> 6;
    #pragma unroll
    for (int w = 0; w < NQB; ++w) {
        float v = acc[w];
        #pragma unroll
        for (int off = 32; off > 0; off >>= 1) v += __shfl_down(v, off);
        if (lane == 0) zpart[wid][w] = v;
    }
    __syncthreads();
    if (tid < NQB) {
        float v = 0.f;
        #pragma unroll
        for (int k = 0; k < TPB / 64; ++k) v += zpart[k][tid];
        zfin[tid] = v * (1.0f / NST);
    }
    __syncthreads();

    // classifier head
    if (tid < NCLS) {
        float a = bias[tid];
        #pragma unroll
        for (int w = 0; w < NQB; ++w) a += zfin[w] * W[tid * NQB + w];
        out[b * NCLS + tid] = a;
    }
}

// ---- host-side static mask computation (pure CPU, graph-capture safe) ----

static int f_of(int j) {
    // one layer's CNOT ring (state'[j] = state[f(j)], wire w <-> bit 11-w)
    for (int w = 11; w >= 0; --w) {
        int pc = 11 - w;
        int pt = 11 - ((w + 1) % 12);
        j ^= ((j >> pc) & 1) << pt;
    }
    return j;
}

static void build_args(PhiArgs* P, MainArgs* M) {
    // layer-l RX on wire w sees accumulated permutation g = f^l:
    // stored-space mask = f^l(2^(11-w)); angle = qw[l*12+w]
    for (int l = 0; l < NLAY; ++l)
        for (int w = 0; w < NQB; ++w) {
            int v = 1 << (11 - w);
            for (int t = 0; t < l; ++t) v = f_of(v);
            P->m[l * NQB + w] = v;
        }
    // measurement parities: rows of (f^6)^-1 over GF(2)
    int col[NQB];
    for (int k = 0; k < NQB; ++k) {
        int v = 1 << k;
        for (int t = 0; t < NLAY; ++t) v = f_of(v);
        col[k] = v;
    }
    unsigned rowG[NQB], rowH[NQB];
    for (int r = 0; r < NQB; ++r) {
        unsigned rr = 0;
        for (int k = 0; k < NQB; ++k) rr |= ((unsigned)((col[k] >> r) & 1)) << k;
        rowG[r] = rr;
        rowH[r] = 1u << r;
    }
    for (int k = 0; k < NQB; ++k) {                  // Gauss-Jordan over GF(2)
        int piv = -1;
        for (int r = k; r < NQB; ++r)
            if ((rowG[r] >> k) & 1) { piv = r; break; }
        unsigned tg = rowG[piv], th = rowH[piv];
        rowG[piv] = rowG[k]; rowH[piv] = rowH[k];
        rowG[k] = tg; rowH[k] = th;
        for (int r = 0; r < NQB; ++r)
            if (r != k && ((rowG[r] >> k) & 1)) { rowG[r] ^= rowG[k]; rowH[r] ^= rowH[k]; }
    }
    for (int w = 0; w < NQB; ++w) M->meas[w] = (int)rowH[11 - w];
}

extern "C" void kernel_launch(void* const* d_in, const int* in_sizes, int n_in,
                              void* d_out, int out_size, void* d_ws, size_t ws_size,
                              hipStream_t stream) {
    const float* x    = (const float*)d_in[0];
    const float* qw   = (const float*)d_in[1];
    const float* W    = (const float*)d_in[2];
    const float* bias = (const float*)d_in[3];
    float* out        = (float*)d_out;
    float* phiq       = (float*)d_ws;      // 4096 floats = 16 KB scratch

    PhiArgs P; MainArgs M;
    build_args(&P, &M);

    const int batch = in_sizes[0] / NQB;   // 512
    phiq_kernel<<<64, 64, 0, stream>>>(qw, phiq, P);
    qnn_kernel<<<batch, TPB, 0, stream>>>(x, phiq, W, bias, out, M);
}

// Round 4
// 70.096 us; speedup vs baseline: 1.9248x; 1.0348x over previous
//
#include <hip/hip_runtime.h>

#define NQB   12
#define NST   4096
#define NLAY  6
#define NCLS  64
#define NGQ   72      // 6 layers x 12 RX gates (sample-independent)
#define TPB   512

struct PhiArgs  { int m[NGQ]; };     // XOR masks (permuted basis) for layer RX
struct MainArgs {
    int   wire_of_bit[NQB];   // new-bit p -> embedding wire index
    int   mlo[NQB];           // t_w & 511
    int   h[NQB];             // t_w >> 9
    int   rmask[NQB];         // which r-slabs to process (0xFF = all)
    float wgt[NQB];           // (1 or 2) / NST, pair-halving weight
};

// ---- kernel 1: Phiq[k] = 0.5 * sum_g (-1)^{popc(k & m_g)} * qw[g] ----
__global__ __launch_bounds__(64) void phiq_kernel(
    const float* __restrict__ qw, float* __restrict__ phiq, PhiArgs A)
{
    const int k = blockIdx.x * 64 + threadIdx.x;   // 64 blocks x 64 = 4096
    float acc = 0.f;
    #pragma unroll
    for (int g = 0; g < NGQ; ++g) {
        float v = 0.5f * qw[g];                    // uniform -> scalar load
        acc += (__popc(k & A.m[g]) & 1) ? -v : v;
    }
    phiq[k] = acc;
}

// ---- kernel 2: per-sample phases, halved Walsh autocorrelation, head ----
__global__ __launch_bounds__(TPB) void qnn_kernel(
    const float* __restrict__ x, const float* __restrict__ phiq,
    const float* __restrict__ W, const float* __restrict__ bias,
    float* __restrict__ out, MainArgs A)
{
    __shared__ float2 d[NST];                 // d_k = (cos phi_k, sin phi_k)
    __shared__ float  zpart[TPB / 64][NQB];
    __shared__ float  zfin[NQB];

    const int tid = threadIdx.x;
    const int b   = blockIdx.x;

    // sample-independent phases (8 coalesced loads, L2-hot 16 KB)
    float pq[8];
    #pragma unroll
    for (int r = 0; r < 8; ++r) pq[r] = phiq[tid + (r << 9)];

    // embedding: each wire is a single bit in the (permuted) basis.
    // k = tid | (r<<9): bits 0..8 from tid, bits 9..11 from r.
    float xl[NQB];
    #pragma unroll
    for (int p = 0; p < NQB; ++p)
        xl[p] = 0.5f * x[b * NQB + A.wire_of_bit[p]];   // uniform idx
    float base = 0.f;
    #pragma unroll
    for (int p = 0; p < 9; ++p)
        base += ((tid >> p) & 1) ? -xl[p] : xl[p];
    float c3[8];
    #pragma unroll
    for (int r = 0; r < 8; ++r)
        c3[r] = ((r & 1) ? -xl[9]  : xl[9])
              + ((r & 2) ? -xl[10] : xl[10])
              + ((r & 4) ? -xl[11] : xl[11]);

    float2 myd[8];
    #pragma unroll
    for (int r = 0; r < 8; ++r) {
        float phi = pq[r] + base + c3[r];
        // v_sin/v_cos take revolutions; phi ~1e2 rad -> ~1e-5 phase error
        // after the fp32 mul, far under the 6e-4 absmax threshold
        float rv = phi * 0.15915494309189535f;
        rv -= floorf(rv);
        float sv = __builtin_amdgcn_sinf(rv);
        float cv = __builtin_amdgcn_cosf(rv);
        myd[r] = make_float2(cv, sv);
        d[tid + (r << 9)] = myd[r];
    }
    __syncthreads();

    // z_w = (1/N) sum_k cos(phi_k - phi_{k^t_w}); pairs counted once and
    // doubled when t_w has a slab-bit (rmask restricts r, wave-uniform skip)
    float acc[NQB];
    #pragma unroll
    for (int w = 0; w < NQB; ++w) {
        const int u  = tid ^ A.mlo[w];
        const int hw = A.h[w];
        float aw = 0.f;
        #pragma unroll
        for (int r = 0; r < 8; ++r) {
            if (A.rmask[w] & (1 << r)) {          // kernarg & const: scalar
                float2 p = d[u | ((hw ^ r) << 9)];
                aw = fmaf(myd[r].x, p.x, fmaf(myd[r].y, p.y, aw));
            }
        }
        acc[w] = aw * A.wgt[w];
    }

    // reduce 12 sums over 512 threads
    const int lane = tid & 63, wid = tid >> 6;
    #pragma unroll
    for (int w = 0; w < NQB; ++w) {
        float v = acc[w];
        #pragma unroll
        for (int off = 32; off > 0; off >>= 1) v += __shfl_down(v, off);
        if (lane == 0) zpart[wid][w] = v;
    }
    __syncthreads();
    if (tid < NQB) {
        float v = 0.f;
        #pragma unroll
        for (int k = 0; k < TPB / 64; ++k) v += zpart[k][tid];
        zfin[tid] = v;                            // weights already applied
    }
    __syncthreads();

    // classifier head
    if (tid < NCLS) {
        float a = bias[tid];
        #pragma unroll
        for (int w = 0; w < NQB; ++w) a += zfin[w] * W[tid * NQB + w];
        out[b * NCLS + tid] = a;
    }
}

// ---- host-side static mask computation (pure CPU, graph-capture safe) ----

static int f_of(int j) {
    // one layer's CNOT ring (natural basis: wire w <-> bit 11-w)
    for (int w = 11; w >= 0; --w) {
        int pc = 11 - w;
        int pt = 11 - ((w + 1) % 12);
        j ^= ((j >> pc) & 1) << pt;
    }
    return j;
}

static void build_args(PhiArgs* P, MainArgs* M) {
    // natural-basis layer masks: layer l, wire w -> f^l(2^(11-w))
    int lm[NGQ];
    for (int l = 0; l < NLAY; ++l)
        for (int w = 0; w < NQB; ++w) {
            int v = 1 << (11 - w);
            for (int t = 0; t < l; ++t) v = f_of(v);
            lm[l * NQB + w] = v;
        }
    // natural-basis measurement parities: rows of (f^6)^-1 over GF(2)
    int col[NQB];
    for (int k = 0; k < NQB; ++k) {
        int v = 1 << k;
        for (int t = 0; t < NLAY; ++t) v = f_of(v);
        col[k] = v;
    }
    unsigned rowG[NQB], rowH[NQB];
    for (int r = 0; r < NQB; ++r) {
        unsigned rr = 0;
        for (int k = 0; k < NQB; ++k) rr |= ((unsigned)((col[k] >> r) & 1)) << k;
        rowG[r] = rr;
        rowH[r] = 1u << r;
    }
    for (int k = 0; k < NQB; ++k) {                  // Gauss-Jordan over GF(2)
        int piv = -1;
        for (int r = k; r < NQB; ++r)
            if ((rowG[r] >> k) & 1) { piv = r; break; }
        unsigned tg = rowG[piv], th = rowH[piv];
        rowG[piv] = rowG[k]; rowH[piv] = rowH[k];
        rowG[k] = tg; rowH[k] = th;
        for (int r = 0; r < NQB; ++r)
            if (r != k && ((rowG[r] >> k) & 1)) { rowG[r] ^= rowG[k]; rowH[r] ^= rowH[k]; }
    }
    int meas_nat[NQB];
    for (int w = 0; w < NQB; ++w) meas_nat[w] = (int)rowH[11 - w];

    // choose 3 natural bits -> slab bits 9..11 maximizing #meas rows covered
    int bc0 = 0, bc1 = 1, bc2 = 2, best = -1;
    for (int a = 0; a < NQB; ++a)
        for (int bb = a + 1; bb < NQB; ++bb)
            for (int c = bb + 1; c < NQB; ++c) {
                int sel = (1 << a) | (1 << bb) | (1 << c), cov = 0;
                for (int w = 0; w < NQB; ++w) if (meas_nat[w] & sel) ++cov;
                if (cov > best) { best = cov; bc0 = a; bc1 = bb; bc2 = c; }
            }
    int sigma[NQB];                 // natural bit j -> new bit sigma[j]
    sigma[bc0] = 9; sigma[bc1] = 10; sigma[bc2] = 11;
    int nxt = 0;
    for (int j = 0; j < NQB; ++j)
        if (j != bc0 && j != bc1 && j != bc2) sigma[j] = nxt++;
    auto pm = [&](int m) {
        int o = 0;
        for (int j = 0; j < NQB; ++j) if ((m >> j) & 1) o |= 1 << sigma[j];
        return o;
    };

    for (int g = 0; g < NGQ; ++g) P->m[g] = pm(lm[g]);
    for (int w = 0; w < NQB; ++w) M->wire_of_bit[sigma[11 - w]] = w;

    for (int w = 0; w < NQB; ++w) {
        int t = pm(meas_nat[w]);
        M->mlo[w] = t & 511;
        M->h[w]   = t >> 9;
        if (M->h[w]) {                 // halve over a slab bit of t
            int bsel = __builtin_ctz(M->h[w]);
            M->rmask[w] = (bsel == 0) ? 0x55 : (bsel == 1) ? 0x33 : 0x0F;
            M->wgt[w]   = 2.0f / NST;
        } else {
            M->rmask[w] = 0xFF;
            M->wgt[w]   = 1.0f / NST;
        }
    }
}

extern "C" void kernel_launch(void* const* d_in, const int* in_sizes, int n_in,
                              void* d_out, int out_size, void* d_ws, size_t ws_size,
                              hipStream_t stream) {
    const float* x    = (const float*)d_in[0];
    const float* qw   = (const float*)d_in[1];
    const float* W    = (const float*)d_in[2];
    const float* bias = (const float*)d_in[3];
    float* out        = (float*)d_out;
    float* phiq       = (float*)d_ws;      // 4096 floats = 16 KB scratch

    PhiArgs P; MainArgs M;
    build_args(&P, &M);

    const int batch = in_sizes[0] / NQB;   // 512
    phiq_kernel<<<64, 64, 0, stream>>>(qw, phiq, P);
    qnn_kernel<<<batch, TPB, 0, stream>>>(x, phiq, W, bias, out, M);
}

// Round 5
// 66.078 us; speedup vs baseline: 2.0418x; 1.0608x over previous
//
#include <hip/hip_runtime.h>

#define NQB   12
#define NST   4096
#define NLAY  6
#define NCLS  64
#define NGQ   72      // 6 layers x 12 RX gates (sample-independent)
#define TPB   512
#define RS    10      // d row stride in float2 (80 B: 16B-aligned, bank-clean)
#define ZST   516     // zmat row stride in dwords (16B-aligned rows)

struct PhiArgs  { int m[NGQ]; };   // transformed layer-RX masks
struct MainArgs {
    int emlo[NQB];   // embedding mask low 9 bits (vs tid)
    int ehi[NQB];    // embedding mask high 3 bits (vs r)
};

// ---- kernel 1: Phiq[j] = 0.5 * sum_g (-1)^{popc(j & m'_g)} * qw[g] ----
__global__ __launch_bounds__(64) void phiq_kernel(
    const float* __restrict__ qw, float* __restrict__ phiq, PhiArgs A)
{
    const int k = blockIdx.x * 64 + threadIdx.x;   // 64 blocks x 64 = 4096
    float acc = 0.f;
    #pragma unroll
    for (int g = 0; g < NGQ; ++g) {
        float v = 0.5f * qw[g];                    // uniform -> scalar load
        acc += (__popc(k & A.m[g]) & 1) ? -v : v;
    }
    phiq[k] = acc;
}

// ---- kernel 2: phases, single-bit-mask Walsh autocorrelation, head ----
__global__ __launch_bounds__(TPB) void qnn_kernel(
    const float* __restrict__ x, const float* __restrict__ phiq,
    const float* __restrict__ W, const float* __restrict__ bias,
    float* __restrict__ out, MainArgs A)
{
    __shared__ float2 dd[TPB * RS];        // d[tid][r], padded rows
    __shared__ float  zmat[NQB * ZST];     // per-thread partials, [w][tid]
    __shared__ float  part2[NQB * 32];
    __shared__ float  zfin[NQB];

    const int tid = threadIdx.x;
    const int b   = blockIdx.x;

    // sample-independent phases (j = tid | r<<9)
    float pq[8];
    #pragma unroll
    for (int r = 0; r < 8; ++r) pq[r] = phiq[tid + (r << 9)];

    // embedding phases: general 12-bit masks (basis change made meas masks
    // unit bits; embedding masks absorbed the transform)
    float px[8];
    #pragma unroll
    for (int r = 0; r < 8; ++r) px[r] = 0.f;
    #pragma unroll
    for (int w = 0; w < NQB; ++w) {
        float xv = 0.5f * x[b * NQB + w];           // uniform load
        float sv = (__popc(tid & A.emlo[w]) & 1) ? -xv : xv;
        const int hi = A.ehi[w];                    // scalar
        #pragma unroll
        for (int r = 0; r < 8; ++r)
            px[r] += (__popc(r & hi) & 1) ? -sv : sv;
    }

    float2 myd[8];
    #pragma unroll
    for (int r = 0; r < 8; ++r) {
        float phi = pq[r] + px[r];
        // v_sin/v_cos take revolutions; phi ~1e2 rad -> ~1e-5 phase error,
        // far under the 6e-4 absmax threshold
        float rv = phi * 0.15915494309189535f;
        rv -= floorf(rv);
        myd[r] = make_float2(__builtin_amdgcn_cosf(rv),
                             __builtin_amdgcn_sinf(rv));
    }
    // write own row as 4 x b128 (80 B row stride: conflict-free)
    {
        float4* wr = (float4*)&dd[tid * RS];
        #pragma unroll
        for (int h = 0; h < 4; ++h)
            wr[h] = make_float4(myd[2 * h].x, myd[2 * h].y,
                                myd[2 * h + 1].x, myd[2 * h + 1].y);
    }
    __syncthreads();

    // z_w for meas mask e_p. p<6: lane bit (exec-masked half, pairs once);
    // p=6..8: wave bit (wave-uniform skip); p=9..11: register slab bit.
    float acc[NQB];
    #pragma unroll
    for (int p = 0; p < 9; ++p) {
        float aw = 0.f;
        if (!((tid >> p) & 1)) {
            const float4* row = (const float4*)&dd[(tid ^ (1 << p)) * RS];
            #pragma unroll
            for (int h = 0; h < 4; ++h) {
                float4 q = row[h];                 // (c,s) for r=2h, 2h+1
                aw = fmaf(myd[2 * h].x, q.x, fmaf(myd[2 * h].y, q.y, aw));
                aw = fmaf(myd[2 * h + 1].x, q.z,
                          fmaf(myd[2 * h + 1].y, q.w, aw));
            }
        }
        acc[p] = aw;
    }
    {
        auto dot2 = [&](int i, int j) {
            return fmaf(myd[i].x, myd[j].x, myd[i].y * myd[j].y);
        };
        acc[9]  = dot2(0,1) + dot2(2,3) + dot2(4,5) + dot2(6,7);  // r^1 pairs
        acc[10] = dot2(0,2) + dot2(1,3) + dot2(4,6) + dot2(5,7);  // r^2 pairs
        acc[11] = dot2(0,4) + dot2(1,5) + dot2(2,6) + dot2(3,7);  // r^4 pairs
    }

    // two-stage LDS reduction (replaces 72 shfl ops on the LDS pipe)
    #pragma unroll
    for (int w = 0; w < NQB; ++w) zmat[w * ZST + tid] = acc[w];
    __syncthreads();
    if (tid < NQB * 32) {
        const int w = tid >> 5, seg = tid & 31;
        const float4* rowz = (const float4*)&zmat[w * ZST];
        float s = 0.f;
        #pragma unroll
        for (int i = 0; i < 4; ++i) {
            float4 q = rowz[seg * 4 + i];
            s += (q.x + q.y) + (q.z + q.w);
        }
        part2[w * 32 + seg] = s;
    }
    __syncthreads();
    if (tid < NQB) {
        float s = 0.f;
        #pragma unroll
        for (int i = 0; i < 32; ++i) s += part2[tid * 32 + i];
        zfin[tid] = s * (2.0f / NST);   // every pair counted once -> x2
    }
    __syncthreads();

    // classifier head
    if (tid < NCLS) {
        float a = bias[tid];
        #pragma unroll
        for (int w = 0; w < NQB; ++w) a += zfin[w] * W[tid * NQB + w];
        out[b * NCLS + tid] = a;
    }
}

// ---- host-side static mask computation (pure CPU, graph-capture safe) ----

static int f_of(int j) {
    // one layer's CNOT ring (natural basis: wire w <-> bit 11-w)
    for (int w = 11; w >= 0; --w) {
        int pc = 11 - w;
        int pt = 11 - ((w + 1) % 12);
        j ^= ((j >> pc) & 1) << pt;
    }
    return j;
}

static void build_args(PhiArgs* P, MainArgs* M) {
    // natural-basis layer masks: layer l, wire w -> f^l(2^(11-w))
    int lm[NGQ];
    for (int l = 0; l < NLAY; ++l)
        for (int w = 0; w < NQB; ++w) {
            int v = 1 << (11 - w);
            for (int t = 0; t < l; ++t) v = f_of(v);
            lm[l * NQB + w] = v;
        }
    // natural-basis measurement parities: rows of (f^6)^-1 over GF(2)
    int col[NQB];
    for (int k = 0; k < NQB; ++k) {
        int v = 1 << k;
        for (int t = 0; t < NLAY; ++t) v = f_of(v);
        col[k] = v;
    }
    unsigned rowG[NQB], rowH[NQB];
    for (int r = 0; r < NQB; ++r) {
        unsigned rr = 0;
        for (int k = 0; k < NQB; ++k) rr |= ((unsigned)((col[k] >> r) & 1)) << k;
        rowG[r] = rr;
        rowH[r] = 1u << r;
    }
    for (int k = 0; k < NQB; ++k) {                  // Gauss-Jordan over GF(2)
        int piv = -1;
        for (int r = k; r < NQB; ++r)
            if ((rowG[r] >> k) & 1) { piv = r; break; }
        unsigned tg = rowG[piv], th = rowH[piv];
        rowG[piv] = rowG[k]; rowH[piv] = rowH[k];
        rowG[k] = tg; rowH[k] = th;
        for (int r = 0; r < NQB; ++r)
            if (r != k && ((rowG[r] >> k) & 1)) { rowG[r] ^= rowG[k]; rowH[r] ^= rowH[k]; }
    }
    int meas_nat[NQB];
    for (int w = 0; w < NQB; ++w) meas_nat[w] = (int)rowH[11 - w];

    // Basis change S with S(t_w) = e_w. S^-1 = Tm where Tm[w] = t_w.
    // Masks transform by S^-T: bit b of m' = parity(popc(Tm[b] & m)).
    int Tm[NQB];
    for (int w = 0; w < NQB; ++w) Tm[w] = meas_nat[w];
    auto xf = [&](int m) {
        int o = 0;
        for (int bb = 0; bb < NQB; ++bb)
            if (__builtin_popcount((unsigned)(Tm[bb] & m)) & 1) o |= 1 << bb;
        return o;
    };
    for (int g = 0; g < NGQ; ++g) P->m[g] = xf(lm[g]);
    for (int w = 0; w < NQB; ++w) {
        int e = xf(1 << (11 - w));     // embedding RX on wire w
        M->emlo[w] = e & 511;
        M->ehi[w]  = e >> 9;
    }
}

extern "C" void kernel_launch(void* const* d_in, const int* in_sizes, int n_in,
                              void* d_out, int out_size, void* d_ws, size_t ws_size,
                              hipStream_t stream) {
    const float* x    = (const float*)d_in[0];
    const float* qw   = (const float*)d_in[1];
    const float* W    = (const float*)d_in[2];
    const float* bias = (const float*)d_in[3];
    float* out        = (float*)d_out;
    float* phiq       = (float*)d_ws;      // 4096 floats = 16 KB scratch

    PhiArgs P; MainArgs M;
    build_args(&P, &M);

    const int batch = in_sizes[0] / NQB;   // 512
    phiq_kernel<<<64, 64, 0, stream>>>(qw, phiq, P);
    qnn_kernel<<<batch, TPB, 0, stream>>>(x, phiq, W, bias, out, M);
}